// Round 2
// baseline (1103.283 us; speedup 1.0000x reference)
//
#include <hip/hip_runtime.h>

// Problem constants
#define CDIM 256        // token_size (channels)
#define CB   4096       // codebook size
#define HW   1024       // 32*32
#define NTOK 32768      // 32*32*32 tokens
#define NELEM 8388608   // 32*256*32*32

// k1 tiling
#define MT 128          // tokens per block
#define NT 128          // codes per tile
#define KCH 32          // K-chunk

// ---------------- kernel 0: codebook row norms + zero the loss accumulator ----------------
__global__ __launch_bounds__(256) void k0_enorm(const float* __restrict__ emb,
                                                float* __restrict__ enorm2,
                                                float* __restrict__ S) {
    const int code = blockIdx.x * 256 + threadIdx.x;   // grid = 16 blocks
    const float4* row = (const float4*)(emb + (size_t)code * CDIM);
    float s = 0.f;
#pragma unroll 8
    for (int i = 0; i < CDIM / 4; ++i) {
        float4 v = row[i];
        s += v.x * v.x + v.y * v.y + v.z * v.z + v.w * v.w;
    }
    enorm2[code] = s;
    if (blockIdx.x == 0 && threadIdx.x == 0) *S = 0.f;
}

// ---------------- kernel 0z: per-token ||z||^2 ----------------
// Any fp32 summation order is fine: argmin decisions are invariant to
// grid-multiple translations of znorm2 (see session notes).
__global__ __launch_bounds__(256) void k0z_znorm(const float* __restrict__ z,
                                                 float* __restrict__ znorm2) {
    const int tok = blockIdx.x * 256 + threadIdx.x;    // grid = 128 blocks
    const int b   = tok >> 10;
    const int hw  = tok & 1023;
    const float* zp = z + (size_t)b * (CDIM * HW) + hw;
    float s0 = 0.f, s1 = 0.f, s2 = 0.f, s3 = 0.f;
#pragma unroll 4
    for (int c = 0; c < CDIM; c += 4) {
        float a = zp[(size_t)(c + 0) * HW];
        float b2 = zp[(size_t)(c + 1) * HW];
        float c2 = zp[(size_t)(c + 2) * HW];
        float d2 = zp[(size_t)(c + 3) * HW];
        s0 += a * a; s1 += b2 * b2; s2 += c2 * c2; s3 += d2 * d2;
    }
    znorm2[tok] = (s0 + s1) + (s2 + s3);
}

// ---------------- kernel 1: tiled GEMM-argmin (reference-rounding replica) ----------------
// d_k = fl32( fl32(znorm2 + enorm2_k) - 2*dot_k ), argmin w/ first-index tie-break.
__global__ __launch_bounds__(256) void k1_argmin(const float* __restrict__ z,
                                                 const float* __restrict__ emb,
                                                 const float* __restrict__ enorm2,
                                                 const float* __restrict__ znorm2,
                                                 float* __restrict__ idxf,
                                                 float* __restrict__ S) {
    __shared__ float Zs[KCH][MT + 4];   // [c][token], pad 128->132
    __shared__ float Es[KCH][NT + 4];   // [c][code],  pad 128->132

    const int tid  = threadIdx.x;
    const int tok0 = blockIdx.x * MT;          // grid = 256 blocks
    const int b    = tok0 >> 10;
    const int hw0  = tok0 & 1023;              // MT | 1024 -> block never crosses b
    const float* zb = z + (size_t)b * (CDIM * HW) + hw0;

    const int tx = tid & 15;                   // tokens 8*tx .. 8*tx+7
    const int ty = tid >> 4;                   // codes  8*ty .. 8*ty+7 (per tile)

    // per-token ||z||^2 (fp32, as the reference adds it)
    float4 zn0 = *(const float4*)(znorm2 + tok0 + 8 * tx);
    float4 zn1 = *(const float4*)(znorm2 + tok0 + 8 * tx + 4);
    const float zn[8] = {zn0.x, zn0.y, zn0.z, zn0.w, zn1.x, zn1.y, zn1.z, zn1.w};

    float bestd[8];
    int   bestk[8];
#pragma unroll
    for (int i = 0; i < 8; ++i) { bestd[i] = 1e30f; bestk[i] = 0; }

    for (int ct = 0; ct < CB / NT; ++ct) {
        const int code0 = ct * NT;
        float acc[8][8];
#pragma unroll
        for (int i = 0; i < 8; ++i)
#pragma unroll
            for (int j = 0; j < 8; ++j) acc[i][j] = 0.f;

        for (int kc = 0; kc < CDIM / KCH; ++kc) {
            const int c0 = kc * KCH;
            __syncthreads();
            // stage Z chunk: 128 tokens x 32 c  (coalesced float4 along tokens)
            {
                const int t4 = (tid & 31) * 4;
                int kk = tid >> 5;             // 0..7, 4 passes
#pragma unroll
                for (int p = 0; p < 4; ++p, kk += 8) {
                    float4 v = *(const float4*)(zb + (size_t)(c0 + kk) * HW + t4);
                    *(float4*)&Zs[kk][t4] = v;
                }
            }
            // stage E chunk: 128 codes x 32 c (float4 along c, transposed scalar LDS stores)
            {
                const int code  = tid >> 1;
                const int kbase = (tid & 1) * 16;
                const float* er = emb + (size_t)(code0 + code) * CDIM + c0 + kbase;
#pragma unroll
                for (int q = 0; q < 4; ++q) {
                    float4 v = *(const float4*)(er + 4 * q);
                    Es[kbase + 4 * q + 0][code] = v.x;
                    Es[kbase + 4 * q + 1][code] = v.y;
                    Es[kbase + 4 * q + 2][code] = v.z;
                    Es[kbase + 4 * q + 3][code] = v.w;
                }
            }
            __syncthreads();
#pragma unroll
            for (int k = 0; k < KCH; ++k) {
                float4 a0 = *(const float4*)&Zs[k][8 * tx];
                float4 a1 = *(const float4*)&Zs[k][8 * tx + 4];
                float4 b0 = *(const float4*)&Es[k][8 * ty];
                float4 b1 = *(const float4*)&Es[k][8 * ty + 4];
                float av[8] = {a0.x, a0.y, a0.z, a0.w, a1.x, a1.y, a1.z, a1.w};
                float bv[8] = {b0.x, b0.y, b0.z, b0.w, b1.x, b1.y, b1.z, b1.w};
#pragma unroll
                for (int i = 0; i < 8; ++i)
#pragma unroll
                    for (int j = 0; j < 8; ++j) acc[i][j] += av[i] * bv[j];
            }
        }
        // epilogue: replicate reference rounding chain exactly:
        //   t1 = fl(zn + en_k); d = fl(t1 - 2*dot)   (2*dot is exact; fma contraction harmless)
        float4 e0 = *(const float4*)(enorm2 + code0 + 8 * ty);
        float4 e1 = *(const float4*)(enorm2 + code0 + 8 * ty + 4);
        const float en[8] = {e0.x, e0.y, e0.z, e0.w, e1.x, e1.y, e1.z, e1.w};
#pragma unroll
        for (int i = 0; i < 8; ++i) {
#pragma unroll
            for (int j = 0; j < 8; ++j) {
                float t1 = zn[i] + en[j];
                float d  = t1 - 2.f * acc[i][j];
                if (d < bestd[i]) { bestd[i] = d; bestk[i] = code0 + 8 * ty + j; }
            }
        }
    }

    // cross-ty reduction via LDS reuse; ties on the quantized grid -> lowest index wins
    __syncthreads();
    float* redd = &Zs[0][0];       // 2048 floats needed; 132*32 available
    int*   redk = (int*)&Es[0][0];
#pragma unroll
    for (int i = 0; i < 8; ++i) {
        redd[ty * MT + 8 * tx + i] = bestd[i];
        redk[ty * MT + 8 * tx + i] = bestk[i];
    }
    __syncthreads();
    if (tid < MT) {
        float bd = 1e30f; int bk = 0x7fffffff;
        for (int t = 0; t < 16; ++t) {
            float d2 = redd[t * MT + tid];
            int   k2 = redk[t * MT + tid];
            if (d2 < bd || (d2 == bd && k2 < bk)) { bd = d2; bk = k2; }
        }
        idxf[tok0 + tid] = (float)bk;   // indices emitted as float32
        // stash per-token min distance (already includes ||z||^2) for the loss
        redd[tid] = bd;
    }
    __syncthreads();
    if (tid == 0) {
        float s = 0.f;
        for (int t = 0; t < MT; ++t) s += redd[t];
        atomicAdd(S, s);               // device-scope by default
    }
}

// ---------------- kernel 2: scatter z_q = emb[idx] into [b,c,h,w] layout ----------------
__global__ __launch_bounds__(256) void k2_scatter(const float* __restrict__ emb,
                                                  const float* __restrict__ idxf,
                                                  float* __restrict__ zq) {
    __shared__ int ks[64];
    const int tid  = threadIdx.x;
    const int tok0 = blockIdx.x * 64;          // grid = 512 blocks
    const int b    = tok0 >> 10;
    const int hw0  = tok0 & 1023;
    if (tid < 64) ks[tid] = (int)idxf[tok0 + tid];
    __syncthreads();
    const int t4 = (tid & 15) * 4;
    const int ka = ks[t4], kb = ks[t4 + 1], kc = ks[t4 + 2], kd = ks[t4 + 3];
    float* outb = zq + (size_t)b * (CDIM * HW) + hw0 + t4;
    int c = tid >> 4;                          // 16 c per pass, 16 passes
#pragma unroll
    for (int p = 0; p < 16; ++p, c += 16) {
        float4 v;
        v.x = emb[(size_t)ka * CDIM + c];
        v.y = emb[(size_t)kb * CDIM + c];
        v.z = emb[(size_t)kc * CDIM + c];
        v.w = emb[(size_t)kd * CDIM + c];
        *(float4*)(outb + (size_t)c * HW) = v;   // coalesced float4 store
    }
}

// ---------------- kernel 3: the three loss scalars ----------------
// S = sum_n min_k ||z_n - e_k||^2  (quantized; error ~1e-3 vs ~2% threshold)
__global__ void k3_scalars(const float* __restrict__ S, float* __restrict__ out) {
    const float mse = *S / (float)NELEM;
    out[0] = 1.25f * mse;   // loss
    out[1] = 0.25f * mse;   // commitment_loss
    out[2] = mse;           // codebook_loss
}

extern "C" void kernel_launch(void* const* d_in, const int* in_sizes, int n_in,
                              void* d_out, int out_size, void* d_ws, size_t ws_size,
                              hipStream_t stream) {
    const float* z   = (const float*)d_in[0];   // [32,256,32,32]
    const float* emb = (const float*)d_in[1];   // [4096,256]
    float* out  = (float*)d_out;                // zq(8388608) | 3 scalars | idx(32768) as f32
    float* wsf  = (float*)d_ws;
    float* S      = wsf;                        // 1 float
    float* enorm2 = wsf + 64;                   // 4096 floats
    float* znorm2 = wsf + 64 + CB;              // 32768 floats
    float* idxf   = out + NELEM + 3;

    hipLaunchKernelGGL(k0_enorm,  dim3(CB / 256),   dim3(256), 0, stream, emb, enorm2, S);
    hipLaunchKernelGGL(k0z_znorm, dim3(NTOK / 256), dim3(256), 0, stream, z, znorm2);
    hipLaunchKernelGGL(k1_argmin, dim3(NTOK / MT),  dim3(256), 0, stream, z, emb, enorm2, znorm2, idxf, S);
    hipLaunchKernelGGL(k2_scatter, dim3(NTOK / 64), dim3(256), 0, stream, emb, idxf, out);
    hipLaunchKernelGGL(k3_scalars, dim3(1), dim3(1), 0, stream, S, out + NELEM);
}

// Round 3
// 897.056 us; speedup vs baseline: 1.2299x; 1.2299x over previous
//
#include <hip/hip_runtime.h>

// Problem constants
#define CDIM 256        // token_size (channels)
#define CB   4096       // codebook size
#define HW   1024       // 32*32
#define NTOK 32768      // 32*32*32 tokens
#define NELEM 8388608   // 32*256*32*32

// k1 tiling
#define MT 128          // tokens per block
#define NT 128          // codes per tile
#define KCH 32          // K-chunk
#define CSPLIT 2        // codebook split -> 2 blocks/CU
#define ZSTRIDE 192     // 16 groups x (8 tokens + 4 pad) floats per k-row

// ---------------- kernel 0: codebook row norms + zero the loss accumulator ----------------
__global__ __launch_bounds__(256) void k0_enorm(const float* __restrict__ emb,
                                                float* __restrict__ enorm2,
                                                float* __restrict__ S) {
    const int code = blockIdx.x * 256 + threadIdx.x;   // grid = 16 blocks
    const float4* row = (const float4*)(emb + (size_t)code * CDIM);
    float s = 0.f;
#pragma unroll 8
    for (int i = 0; i < CDIM / 4; ++i) {
        float4 v = row[i];
        s += v.x * v.x + v.y * v.y + v.z * v.z + v.w * v.w;
    }
    enorm2[code] = s;
    if (blockIdx.x == 0 && threadIdx.x == 0) *S = 0.f;
}

// ---------------- kernel 0z: per-token ||z||^2 ----------------
// Any fp32 summation order works: argmin decisions are invariant to
// grid-multiple translations of znorm2.
__global__ __launch_bounds__(256) void k0z_znorm(const float* __restrict__ z,
                                                 float* __restrict__ znorm2) {
    const int tok = blockIdx.x * 256 + threadIdx.x;    // grid = 128 blocks
    const int b   = tok >> 10;
    const int hw  = tok & 1023;
    const float* zp = z + (size_t)b * (CDIM * HW) + hw;
    float s0 = 0.f, s1 = 0.f, s2 = 0.f, s3 = 0.f;
#pragma unroll 4
    for (int c = 0; c < CDIM; c += 4) {
        float a = zp[(size_t)(c + 0) * HW];
        float b2 = zp[(size_t)(c + 1) * HW];
        float c2 = zp[(size_t)(c + 2) * HW];
        float d2 = zp[(size_t)(c + 3) * HW];
        s0 += a * a; s1 += b2 * b2; s2 += c2 * c2; s3 += d2 * d2;
    }
    znorm2[tok] = (s0 + s1) + (s2 + s3);
}

// ---------------- kernel 1: tiled GEMM-argmin over a codebook slice ----------------
// d_k = fl32( fl32(znorm2 + enorm2_k) - 2*dot_k ); per-(token,split) best -> ws.
__global__ __launch_bounds__(256) void k1_argmin(const float* __restrict__ z,
                                                 const float* __restrict__ emb,
                                                 const float* __restrict__ enorm2,
                                                 const float* __restrict__ znorm2,
                                                 float* __restrict__ wsd,
                                                 int* __restrict__ wsk) {
    // Zs: [k][group g][8 tokens + 4 pad] -> group start bank = (12g)%32, 2-way max (free)
    __shared__ float Zs[KCH][ZSTRIDE];  // 24576 B
    __shared__ float Es[KCH][NT + 4];   // 16896 B, reads are quarter-wave broadcast (conflict-free)

    const int tid   = threadIdx.x;
    const int split = blockIdx.x & (CSPLIT - 1);
    const int tok0  = (blockIdx.x >> 1) * MT;  // 256 token-groups x CSPLIT
    const int b     = tok0 >> 10;
    const int hw0   = tok0 & 1023;             // MT | 1024 -> block never crosses b
    const float* zb = z + (size_t)b * (CDIM * HW) + hw0;

    const int tx = tid & 15;                   // tokens 8*tx .. 8*tx+7
    const int ty = tid >> 4;                   // codes  8*ty .. 8*ty+7 (per tile)

    // per-token ||z||^2 (fp32, as the reference adds it)
    float4 zn0 = *(const float4*)(znorm2 + tok0 + 8 * tx);
    float4 zn1 = *(const float4*)(znorm2 + tok0 + 8 * tx + 4);
    const float zn[8] = {zn0.x, zn0.y, zn0.z, zn0.w, zn1.x, zn1.y, zn1.z, zn1.w};

    float bestd[8];
    int   bestk[8];
#pragma unroll
    for (int i = 0; i < 8; ++i) { bestd[i] = 1e30f; bestk[i] = 0; }

    for (int ct = 0; ct < CB / CSPLIT / NT; ++ct) {
        const int code0 = split * (CB / CSPLIT) + ct * NT;
        float acc[8][8];
#pragma unroll
        for (int i = 0; i < 8; ++i)
#pragma unroll
            for (int j = 0; j < 8; ++j) acc[i][j] = 0.f;

        for (int kc = 0; kc < CDIM / KCH; ++kc) {
            const int c0 = kc * KCH;
            __syncthreads();
            // stage Z chunk: 128 tokens x 32 c (coalesced float4 along tokens,
            // stored into the group-padded layout)
            {
                const int m = tid & 31;                  // tokens 4m..4m+3
                const int zoff = 12 * (m >> 1) + 4 * (m & 1);
                int kk = tid >> 5;                       // 0..7, 4 passes
#pragma unroll
                for (int p = 0; p < 4; ++p, kk += 8) {
                    float4 v = *(const float4*)(zb + (size_t)(c0 + kk) * HW + 4 * m);
                    *(float4*)&Zs[kk][zoff] = v;
                }
            }
            // stage E chunk: 128 codes x 32 c (float4 along c, transposed scalar
            // LDS stores; lane pairs hit same bank = 2-way = free)
            {
                const int code  = tid >> 1;
                const int kbase = (tid & 1) * 16;
                const float* er = emb + (size_t)(code0 + code) * CDIM + c0 + kbase;
#pragma unroll
                for (int q = 0; q < 4; ++q) {
                    float4 v = *(const float4*)(er + 4 * q);
                    Es[kbase + 4 * q + 0][code] = v.x;
                    Es[kbase + 4 * q + 1][code] = v.y;
                    Es[kbase + 4 * q + 2][code] = v.z;
                    Es[kbase + 4 * q + 3][code] = v.w;
                }
            }
            __syncthreads();
#pragma unroll
            for (int k = 0; k < KCH; ++k) {
                float4 a0 = *(const float4*)&Zs[k][12 * tx];
                float4 a1 = *(const float4*)&Zs[k][12 * tx + 4];
                float4 b0 = *(const float4*)&Es[k][8 * ty];
                float4 b1 = *(const float4*)&Es[k][8 * ty + 4];
                float av[8] = {a0.x, a0.y, a0.z, a0.w, a1.x, a1.y, a1.z, a1.w};
                float bv[8] = {b0.x, b0.y, b0.z, b0.w, b1.x, b1.y, b1.z, b1.w};
#pragma unroll
                for (int i = 0; i < 8; ++i)
#pragma unroll
                    for (int j = 0; j < 8; ++j) acc[i][j] += av[i] * bv[j];
            }
        }
        // epilogue: replicate reference rounding chain:
        //   t1 = fl(zn + en_k); d = fl(t1 - 2*dot)
        float4 e0 = *(const float4*)(enorm2 + code0 + 8 * ty);
        float4 e1 = *(const float4*)(enorm2 + code0 + 8 * ty + 4);
        const float en[8] = {e0.x, e0.y, e0.z, e0.w, e1.x, e1.y, e1.z, e1.w};
#pragma unroll
        for (int i = 0; i < 8; ++i) {
#pragma unroll
            for (int j = 0; j < 8; ++j) {
                float t1 = zn[i] + en[j];
                float d  = t1 - 2.f * acc[i][j];
                if (d < bestd[i]) { bestd[i] = d; bestk[i] = code0 + 8 * ty + j; }
            }
        }
    }

    // cross-ty reduction via LDS reuse; ties -> lowest index
    __syncthreads();
    float* redd = &Zs[0][0];       // need 2048 floats; 6144 available
    int*   redk = (int*)&Es[0][0];
#pragma unroll
    for (int i = 0; i < 8; ++i) {
        redd[ty * MT + 8 * tx + i] = bestd[i];
        redk[ty * MT + 8 * tx + i] = bestk[i];
    }
    __syncthreads();
    if (tid < MT) {
        float bd = 1e30f; int bk = 0x7fffffff;
        for (int t = 0; t < 16; ++t) {
            float d2 = redd[t * MT + tid];
            int   k2 = redk[t * MT + tid];
            if (d2 < bd || (d2 == bd && k2 < bk)) { bd = d2; bk = k2; }
        }
        wsd[(size_t)split * NTOK + tok0 + tid] = bd;
        wsk[(size_t)split * NTOK + tok0 + tid] = bk;
    }
}

// ---------------- kernel 4: merge splits, emit indices, accumulate loss sum ----------------
__global__ __launch_bounds__(256) void k4_merge(const float* __restrict__ wsd,
                                                const int* __restrict__ wsk,
                                                float* __restrict__ idxf,
                                                float* __restrict__ S) {
    __shared__ float red[256];
    const int t = blockIdx.x * 256 + threadIdx.x;   // grid = 128 blocks
    float bd = wsd[t];
    int   bk = wsk[t];
#pragma unroll
    for (int s = 1; s < CSPLIT; ++s) {
        float d = wsd[(size_t)s * NTOK + t];
        int   k = wsk[(size_t)s * NTOK + t];
        if (d < bd) { bd = d; bk = k; }   // tie -> lower split = lower index (argmin semantics)
    }
    idxf[t] = (float)bk;
    red[threadIdx.x] = bd;
    __syncthreads();
    for (int o = 128; o > 0; o >>= 1) {
        if (threadIdx.x < o) red[threadIdx.x] += red[threadIdx.x + o];
        __syncthreads();
    }
    if (threadIdx.x == 0) atomicAdd(S, red[0]);
}

// ---------------- kernel 2: scatter z_q = emb[idx] into [b,c,h,w] layout ----------------
__global__ __launch_bounds__(256) void k2_scatter(const float* __restrict__ emb,
                                                  const float* __restrict__ idxf,
                                                  float* __restrict__ zq) {
    __shared__ int ks[64];
    const int tid  = threadIdx.x;
    const int tok0 = blockIdx.x * 64;          // grid = 512 blocks
    const int b    = tok0 >> 10;
    const int hw0  = tok0 & 1023;
    if (tid < 64) ks[tid] = (int)idxf[tok0 + tid];
    __syncthreads();
    const int t4 = (tid & 15) * 4;
    const int ka = ks[t4], kb = ks[t4 + 1], kc = ks[t4 + 2], kd = ks[t4 + 3];
    float* outb = zq + (size_t)b * (CDIM * HW) + hw0 + t4;
    int c = tid >> 4;                          // 16 c per pass, 16 passes
#pragma unroll
    for (int p = 0; p < 16; ++p, c += 16) {
        float4 v;
        v.x = emb[(size_t)ka * CDIM + c];
        v.y = emb[(size_t)kb * CDIM + c];
        v.z = emb[(size_t)kc * CDIM + c];
        v.w = emb[(size_t)kd * CDIM + c];
        *(float4*)(outb + (size_t)c * HW) = v;   // coalesced float4 store
    }
}

// ---------------- kernel 3: the three loss scalars ----------------
// S = sum_n min_k ||z_n - e_k||^2 (quantized d; error ~1e-3 vs ~2% threshold)
__global__ void k3_scalars(const float* __restrict__ S, float* __restrict__ out) {
    const float mse = *S / (float)NELEM;
    out[0] = 1.25f * mse;   // loss
    out[1] = 0.25f * mse;   // commitment_loss
    out[2] = mse;           // codebook_loss
}

extern "C" void kernel_launch(void* const* d_in, const int* in_sizes, int n_in,
                              void* d_out, int out_size, void* d_ws, size_t ws_size,
                              hipStream_t stream) {
    const float* z   = (const float*)d_in[0];   // [32,256,32,32]
    const float* emb = (const float*)d_in[1];   // [4096,256]
    float* out  = (float*)d_out;                // zq(8388608) | 3 scalars | idx(32768) as f32
    float* wsf  = (float*)d_ws;
    float* S      = wsf;                        // 1 float
    float* enorm2 = wsf + 64;                   // 4096
    float* znorm2 = wsf + 64 + CB;              // 32768
    float* wsd    = wsf + 64 + CB + NTOK;       // CSPLIT*32768
    int*   wsk    = (int*)(wsd + (size_t)CSPLIT * NTOK);  // CSPLIT*32768
    float* idxf   = out + NELEM + 3;

    hipLaunchKernelGGL(k0_enorm,  dim3(CB / 256),          dim3(256), 0, stream, emb, enorm2, S);
    hipLaunchKernelGGL(k0z_znorm, dim3(NTOK / 256),        dim3(256), 0, stream, z, znorm2);
    hipLaunchKernelGGL(k1_argmin, dim3(NTOK / MT * CSPLIT), dim3(256), 0, stream,
                       z, emb, enorm2, znorm2, wsd, wsk);
    hipLaunchKernelGGL(k4_merge,  dim3(NTOK / 256),        dim3(256), 0, stream, wsd, wsk, idxf, S);
    hipLaunchKernelGGL(k2_scatter, dim3(NTOK / 64),        dim3(256), 0, stream, emb, idxf, out);
    hipLaunchKernelGGL(k3_scalars, dim3(1), dim3(1), 0, stream, S, out + NELEM);
}